// Round 10
// baseline (263.722 us; speedup 1.0000x reference)
//
#include <hip/hip_runtime.h>
#include <hip/hip_bf16.h>

#define NT 8192      // tokens
#define DM 512       // d_model
#define DF 1024      // d_ff
#define NE 8         // experts
#define MAXROWS (NT*2)
#define MAXT64 264   // sum ceil(cnt_e/64) <= 16384/64 + 8

typedef __bf16 bf16_8 __attribute__((ext_vector_type(8)));
typedef float  f32_4  __attribute__((ext_vector_type(4)));
typedef unsigned short us8 __attribute__((ext_vector_type(8)));

__device__ inline unsigned short f2bf(float f) {
    unsigned int u = __float_as_uint(f);
    u = u + 0x7fffu + ((u >> 16) & 1u);   // RNE
    return (unsigned short)(u >> 16);
}

__device__ inline bf16_8 as_bf(us8 v) { return __builtin_bit_cast(bf16_8, v); }

// ---------------- cast f32 -> bf16 (4 elems/thread) ----------------
__global__ __launch_bounds__(256) void cast_kernel(const float* __restrict__ in,
                                                   unsigned short* __restrict__ out,
                                                   int n4) {
    int i = blockIdx.x * 256 + threadIdx.x;
    if (i >= n4) return;
    float4 v = ((const float4*)in)[i];
    ushort4 o;
    o.x = f2bf(v.x); o.y = f2bf(v.y); o.z = f2bf(v.z); o.w = f2bf(v.w);
    ((ushort4*)out)[i] = o;
}

// ---------------- router phase A: f32 logits, top-2, gates (NO atomics) ----------------
__global__ __launch_bounds__(256) void router_kernel(const float* __restrict__ x,
                                                     const float* __restrict__ wr,
                                                     int* __restrict__ eidx,
                                                     float2* __restrict__ gates) {
    const int wid = threadIdx.x >> 6;
    const int lane = threadIdx.x & 63;
    const int t = blockIdx.x * 4 + wid;

    const float4* xrow = (const float4*)(x + (size_t)t * DM);
    float4 xv0 = xrow[lane * 2];
    float4 xv1 = xrow[lane * 2 + 1];

    float logit[NE];
#pragma unroll
    for (int e = 0; e < NE; ++e) {
        const float4* wrow = (const float4*)(wr + (size_t)e * DM);
        float4 w0 = wrow[lane * 2];
        float4 w1v = wrow[lane * 2 + 1];
        float s = xv0.x * w0.x + xv0.y * w0.y + xv0.z * w0.z + xv0.w * w0.w
                + xv1.x * w1v.x + xv1.y * w1v.y + xv1.z * w1v.z + xv1.w * w1v.w;
#pragma unroll
        for (int off = 32; off >= 1; off >>= 1) s += __shfl_xor(s, off);
        logit[e] = s;
    }

    if (lane == 0) {
        int i0 = 0; float m0 = logit[0];
#pragma unroll
        for (int e = 1; e < NE; ++e) if (logit[e] > m0) { m0 = logit[e]; i0 = e; }
        int i1 = -1; float m1 = -1e30f;
#pragma unroll
        for (int e = 0; e < NE; ++e) if (e != i0 && logit[e] > m1) { m1 = logit[e]; i1 = e; }
        float d = expf(m1 - m0);
        float g0 = 1.0f / (1.0f + d);
        float g1 = 1.0f - g0;
        eidx[t] = i0 | (i1 << 8);
        gates[t] = make_float2(g0, g1);
    }
}

// ---------------- phase B: deterministic expert-list build (8 blocks, 1/expert) ----------------
__global__ __launch_bounds__(256) void build_lists_kernel(const int* __restrict__ eidx,
                                                          const float2* __restrict__ gates,
                                                          int* __restrict__ counts,
                                                          int* __restrict__ token_list,
                                                          float* __restrict__ gate_list) {
    const int e = blockIdx.x;
    const int tid = threadIdx.x;
    const int wid = tid >> 6, lane = tid & 63;
    __shared__ int wsum[4];
    __shared__ int base;
    if (tid == 0) base = 0;
    __syncthreads();
    for (int c = 0; c < NT; c += 256) {
        int t = c + tid;
        int ei = eidx[t];
        int i0 = ei & 0xff, i1 = (ei >> 8) & 0xff;
        bool match0 = (i0 == e), match1 = (i1 == e);
        bool m = match0 || match1;
        unsigned long long mask = __ballot(m);
        if (lane == 0) wsum[wid] = __popcll(mask);
        __syncthreads();
        int pre = 0;
#pragma unroll
        for (int w = 0; w < 4; ++w) if (w < wid) pre += wsum[w];
        int tot = wsum[0] + wsum[1] + wsum[2] + wsum[3];
        if (m) {
            int pos = base + pre + __popcll(mask & ((1ULL << lane) - 1ULL));
            token_list[e * NT + pos] = t;
            float2 g = gates[t];
            gate_list[e * NT + pos] = match0 ? g.x : g.y;
        }
        __syncthreads();
        if (tid == 0) base += tot;
        __syncthreads();
    }
    if (tid == 0) counts[e] = base;
}

// ---------------- scan + dense 64-row tile list ----------------
__global__ void scan_kernel(const int* __restrict__ counts, int* __restrict__ offsets,
                            int* __restrict__ tile_e, int* __restrict__ tile_r0,
                            int* __restrict__ ntiles) {
    if (threadIdx.x == 0) {
        int s = 0, nt = 0;
        for (int e = 0; e < NE; ++e) {
            offsets[e] = s;
            int c = counts[e];
            for (int r0 = 0; r0 < c; r0 += 64) { tile_e[nt] = e; tile_r0[nt] = r0; ++nt; }
            s += c;
        }
        *ntiles = nt;
    }
}

// ---------------- register-direct MoE GEMM: barrier-free, LDS-free ----------------
// Each WAVE owns a 64x64 output tile. A/B fragments load straight from global
// (L2) into registers; fully-unrolled K-loop -> all loads use one base pointer
// + compile-time offset (K-span <= 2KB fits the 13-bit imm). No __shared__, no
// barriers; latency hidden by ~16 independent waves/CU + compiler load hoisting.
template <bool G1>
__global__ __launch_bounds__(256, 4) void moe_gemm(const unsigned short* __restrict__ Abase,
                                                   const unsigned short* __restrict__ Wbase,
                                                   unsigned short* __restrict__ h_out,
                                                   float* __restrict__ out,
                                                   const int* __restrict__ counts,
                                                   const int* __restrict__ offsets,
                                                   const int* __restrict__ token_list,
                                                   const float* __restrict__ gate_list,
                                                   const int* __restrict__ tile_e,
                                                   const int* __restrict__ tile_r0,
                                                   const int* __restrict__ ntiles) {
    constexpr int K = G1 ? DM : DF;       // 512 : 1024
    constexpr int NCOLS = G1 ? DF : DM;   // 1024 : 512
    constexpr int NSTEP = K / 32;         // 16 : 32

    const int tl = blockIdx.y;
    if (tl >= *ntiles) return;
    const int e = tile_e[tl];
    const int row0 = tile_r0[tl];         // 64-granular
    const int cnt = counts[e];
    const int off_e = offsets[e];

    const int wid = threadIdx.x >> 6;
    const int lane = threadIdx.x & 63;
    const int col0 = blockIdx.x * 256 + wid * 64;   // per-wave 64-col slice

    const int lrow = lane & 15;
    const int kc = lane >> 4;             // 0..3 (8-elem K-octet within 32)

    // per-lane base pointers (4 A rows, 4 B rows); all K-steps via const offsets
    const unsigned short* Ap[4];
#pragma unroll
    for (int m = 0; m < 4; ++m) {
        int r = min(row0 + m * 16 + lrow, cnt - 1);
        int row = G1 ? token_list[e * NT + r] : (off_e + r);
        Ap[m] = Abase + (size_t)row * K + kc * 8;
    }
    const unsigned short* Bp[4];
#pragma unroll
    for (int n = 0; n < 4; ++n)
        Bp[n] = Wbase + ((size_t)e * NCOLS + col0 + n * 16 + lrow) * K + kc * 8;

    f32_4 acc[4][4];
#pragma unroll
    for (int m = 0; m < 4; ++m)
#pragma unroll
        for (int n = 0; n < 4; ++n) acc[m][n] = (f32_4){0.f, 0.f, 0.f, 0.f};

#pragma unroll
    for (int t = 0; t < NSTEP; ++t) {
        bf16_8 a[4], b[4];
#pragma unroll
        for (int m = 0; m < 4; ++m) a[m] = as_bf(*(const us8*)(Ap[m] + t * 32));
#pragma unroll
        for (int n = 0; n < 4; ++n) b[n] = as_bf(*(const us8*)(Bp[n] + t * 32));
#pragma unroll
        for (int m = 0; m < 4; ++m)
#pragma unroll
            for (int n = 0; n < 4; ++n)
                acc[m][n] = __builtin_amdgcn_mfma_f32_16x16x32_bf16(a[m], b[n], acc[m][n], 0, 0, 0);
    }

    // epilogue: frag row = (lane>>4)*4 + q, col = lane&15
#pragma unroll
    for (int m = 0; m < 4; ++m) {
#pragma unroll
        for (int n = 0; n < 4; ++n) {
#pragma unroll
            for (int q = 0; q < 4; ++q) {
                int lr = m * 16 + (lane >> 4) * 4 + q;
                int lc = col0 + n * 16 + (lane & 15);
                int r = row0 + lr;
                if (r < cnt) {
                    float v = acc[m][n][q];
                    if (G1) {
                        v = v / (1.0f + expf(-v));  // silu
                        h_out[(size_t)(off_e + r) * DF + lc] = f2bf(v);
                    } else {
                        float g = gate_list[e * NT + r];
                        int tok = token_list[e * NT + r];
                        atomicAdd(&out[(size_t)tok * DM + lc], g * v);
                    }
                }
            }
        }
    }
}

extern "C" void kernel_launch(void* const* d_in, const int* in_sizes, int n_in,
                              void* d_out, int out_size, void* d_ws, size_t ws_size,
                              hipStream_t stream) {
    const float* x   = (const float*)d_in[0];
    const float* wrt = (const float*)d_in[1];
    const float* w1  = (const float*)d_in[2];
    const float* w2  = (const float*)d_in[3];
    float* out = (float*)d_out;

    char* ws = (char*)d_ws;
    size_t o = 0;
    auto alloc = [&](size_t bytes) { size_t r = o; o += (bytes + 255) & ~255UL; return r; };
    unsigned short* x_bf  = (unsigned short*)(ws + alloc((size_t)NT * DM * 2));
    unsigned short* w1_bf = (unsigned short*)(ws + alloc((size_t)NE * DF * DM * 2));
    unsigned short* w2_bf = (unsigned short*)(ws + alloc((size_t)NE * DM * DF * 2));
    unsigned short* h_bf  = (unsigned short*)(ws + alloc((size_t)MAXROWS * DF * 2));
    int*   counts     = (int*)(ws + alloc(NE * 4));
    int*   offsets    = (int*)(ws + alloc(NE * 4));
    int*   token_list = (int*)(ws + alloc((size_t)NE * NT * 4));
    float* gate_list  = (float*)(ws + alloc((size_t)NE * NT * 4));
    int*   eidx       = (int*)(ws + alloc((size_t)NT * 4));
    float2* gates     = (float2*)(ws + alloc((size_t)NT * 8));
    int*   tile_e     = (int*)(ws + alloc(MAXT64 * 4));
    int*   tile_r0    = (int*)(ws + alloc(MAXT64 * 4));
    int*   ntiles     = (int*)(ws + alloc(4));

    hipMemsetAsync(out, 0, (size_t)NT * DM * 4, stream);

    int n4x = NT * DM / 4;
    cast_kernel<<<(n4x + 255) / 256, 256, 0, stream>>>(x, x_bf, n4x);
    int n4w = NE * DF * DM / 4;
    cast_kernel<<<(n4w + 255) / 256, 256, 0, stream>>>(w1, w1_bf, n4w);
    cast_kernel<<<(n4w + 255) / 256, 256, 0, stream>>>(w2, w2_bf, n4w);

    router_kernel<<<NT / 4, 256, 0, stream>>>(x, wrt, eidx, gates);
    build_lists_kernel<<<NE, 256, 0, stream>>>(eidx, gates, counts, token_list, gate_list);
    scan_kernel<<<1, 64, 0, stream>>>(counts, offsets, tile_e, tile_r0, ntiles);

    // GEMM1: 4 waves x 64 cols = 256 cols/block -> 4 col blocks x <=264 row tiles
    moe_gemm<true><<<dim3(DF / 256, MAXT64, 1), 256, 0, stream>>>(
        x_bf, w1_bf, h_bf, nullptr, counts, offsets, token_list, gate_list,
        tile_e, tile_r0, ntiles);
    // GEMM2: 2 col blocks x <=264 row tiles
    moe_gemm<false><<<dim3(DM / 256, MAXT64, 1), 256, 0, stream>>>(
        h_bf, w2_bf, nullptr, out, counts, offsets, token_list, gate_list,
        tile_e, tile_r0, ntiles);
}

// Round 11
// 219.062 us; speedup vs baseline: 1.2039x; 1.2039x over previous
//
#include <hip/hip_runtime.h>
#include <hip/hip_bf16.h>

#define NT 8192      // tokens
#define DM 512       // d_model
#define DF 1024      // d_ff
#define NE 8         // experts
#define MAXROWS (NT*2)
#define MAXT256 72   // sum ceil(cnt_e/256) <= 16384/256 + 8

typedef __bf16 bf16_8 __attribute__((ext_vector_type(8)));
typedef float  f32_4  __attribute__((ext_vector_type(4)));
typedef unsigned short us8 __attribute__((ext_vector_type(8)));

__device__ inline unsigned short f2bf(float f) {
    unsigned int u = __float_as_uint(f);
    u = u + 0x7fffu + ((u >> 16) & 1u);   // RNE
    return (unsigned short)(u >> 16);
}

__device__ inline bf16_8 as_bf(us8 v) { return __builtin_bit_cast(bf16_8, v); }

// async global -> LDS, 16B per lane (lane i lands at ldsbase + i*16)
__device__ inline void gld16(const unsigned short* g, unsigned short* l) {
    __builtin_amdgcn_global_load_lds(
        (const __attribute__((address_space(1))) unsigned int*)g,
        (__attribute__((address_space(3))) unsigned int*)l, 16, 0, 0);
}

// ---------------- cast f32 -> bf16 (4 elems/thread) ----------------
__global__ __launch_bounds__(256) void cast_kernel(const float* __restrict__ in,
                                                   unsigned short* __restrict__ out,
                                                   int n4) {
    int i = blockIdx.x * 256 + threadIdx.x;
    if (i >= n4) return;
    float4 v = ((const float4*)in)[i];
    ushort4 o;
    o.x = f2bf(v.x); o.y = f2bf(v.y); o.z = f2bf(v.z); o.w = f2bf(v.w);
    ((ushort4*)out)[i] = o;
}

// ---------------- router phase A: f32 logits, top-2, gates (NO atomics) ----------------
__global__ __launch_bounds__(256) void router_kernel(const float* __restrict__ x,
                                                     const float* __restrict__ wr,
                                                     int* __restrict__ eidx,
                                                     float2* __restrict__ gates) {
    const int wid = threadIdx.x >> 6;
    const int lane = threadIdx.x & 63;
    const int t = blockIdx.x * 4 + wid;

    const float4* xrow = (const float4*)(x + (size_t)t * DM);
    float4 xv0 = xrow[lane * 2];
    float4 xv1 = xrow[lane * 2 + 1];

    float logit[NE];
#pragma unroll
    for (int e = 0; e < NE; ++e) {
        const float4* wrow = (const float4*)(wr + (size_t)e * DM);
        float4 w0 = wrow[lane * 2];
        float4 w1v = wrow[lane * 2 + 1];
        float s = xv0.x * w0.x + xv0.y * w0.y + xv0.z * w0.z + xv0.w * w0.w
                + xv1.x * w1v.x + xv1.y * w1v.y + xv1.z * w1v.z + xv1.w * w1v.w;
#pragma unroll
        for (int off = 32; off >= 1; off >>= 1) s += __shfl_xor(s, off);
        logit[e] = s;
    }

    if (lane == 0) {
        int i0 = 0; float m0 = logit[0];
#pragma unroll
        for (int e = 1; e < NE; ++e) if (logit[e] > m0) { m0 = logit[e]; i0 = e; }
        int i1 = -1; float m1 = -1e30f;
#pragma unroll
        for (int e = 0; e < NE; ++e) if (e != i0 && logit[e] > m1) { m1 = logit[e]; i1 = e; }
        float d = expf(m1 - m0);
        float g0 = 1.0f / (1.0f + d);
        float g1 = 1.0f - g0;
        eidx[t] = i0 | (i1 << 8);
        gates[t] = make_float2(g0, g1);
    }
}

// ---------------- phase B: deterministic expert-list build (8 blocks, 1/expert) ----------------
__global__ __launch_bounds__(256) void build_lists_kernel(const int* __restrict__ eidx,
                                                          const float2* __restrict__ gates,
                                                          int* __restrict__ counts,
                                                          int* __restrict__ token_list,
                                                          float* __restrict__ gate_list) {
    const int e = blockIdx.x;
    const int tid = threadIdx.x;
    const int wid = tid >> 6, lane = tid & 63;
    __shared__ int wsum[4];
    __shared__ int base;
    if (tid == 0) base = 0;
    __syncthreads();
    for (int c = 0; c < NT; c += 256) {
        int t = c + tid;
        int ei = eidx[t];
        int i0 = ei & 0xff, i1 = (ei >> 8) & 0xff;
        bool match0 = (i0 == e), match1 = (i1 == e);
        bool m = match0 || match1;
        unsigned long long mask = __ballot(m);
        if (lane == 0) wsum[wid] = __popcll(mask);
        __syncthreads();
        int pre = 0;
#pragma unroll
        for (int w = 0; w < 4; ++w) if (w < wid) pre += wsum[w];
        int tot = wsum[0] + wsum[1] + wsum[2] + wsum[3];
        if (m) {
            int pos = base + pre + __popcll(mask & ((1ULL << lane) - 1ULL));
            token_list[e * NT + pos] = t;
            float2 g = gates[t];
            gate_list[e * NT + pos] = match0 ? g.x : g.y;
        }
        __syncthreads();
        if (tid == 0) base += tot;
        __syncthreads();
    }
    if (tid == 0) counts[e] = base;
}

// ---------------- scan + dense 256-row tile list ----------------
__global__ void scan_kernel(const int* __restrict__ counts, int* __restrict__ offsets,
                            int* __restrict__ tile_e, int* __restrict__ tile_r0,
                            int* __restrict__ ntiles) {
    if (threadIdx.x == 0) {
        int s = 0, nt = 0;
        for (int e = 0; e < NE; ++e) {
            offsets[e] = s;
            int c = counts[e];
            for (int r0 = 0; r0 < c; r0 += 256) { tile_e[nt] = e; tile_r0[nt] = r0; ++nt; }
            s += c;
        }
        *ntiles = nt;
    }
}

// ---------------- 8-phase fused MoE GEMM (m201-style port) ----------------
// G1: BM=256 BN=256 BK=64, 8 waves (2Mx4N), per-wave 128x64, 4 phases/K-tile
//     (m-pair x 4n x 2k = 16 MFMA/phase), stage 1 half-tile (2 gld16)/phase,
//     vmcnt(2) once per K-tile at phase 0.
// G2: BM=256 BN=128, per-wave 128x32, 2 phases/K-tile (m-quad x 2n x 2k = 16
//     MFMA/phase), stage A0+A1 at p0 (vmcnt(4)), B at p1.
// Octet XOR swizzle both-sides (proven 0-conflict). B-frags reg-resident/tile.
template <bool G1>
__global__ __launch_bounds__(512, 2) void moe_gemm(const unsigned short* __restrict__ Abase,
                                                   const unsigned short* __restrict__ Wbase,
                                                   unsigned short* __restrict__ h_out,
                                                   float* __restrict__ out,
                                                   const int* __restrict__ counts,
                                                   const int* __restrict__ offsets,
                                                   const int* __restrict__ token_list,
                                                   const float* __restrict__ gate_list,
                                                   const int* __restrict__ tile_e,
                                                   const int* __restrict__ tile_r0,
                                                   const int* __restrict__ ntiles) {
    constexpr int K = G1 ? DM : DF;       // 512 : 1024
    constexpr int NCOLS = G1 ? DF : DM;   // 1024 : 512
    constexpr int BN = G1 ? 256 : 128;
    constexpr int NF = G1 ? 4 : 2;        // n-frags per wave
    constexpr int P  = G1 ? 4 : 2;        // phases per K-tile
    constexpr int MGRP = 8 / P;           // m-frags per phase: 2 : 4
    constexpr int NHB = G1 ? 2 : 1;       // B half-tiles
    constexpr int NK = K / 64;            // 8 : 16
    constexpr int HE = 128 * 64;          // elems per half-tile (16 KB)

    const int tl = blockIdx.y;
    if (tl >= *ntiles) return;
    const int e = tile_e[tl];
    const int row0 = tile_r0[tl];
    const int cnt = counts[e];
    const int col0 = blockIdx.x * BN;
    const int off_e = offsets[e];

    __shared__ __align__(16) unsigned short Alds[2 * 2 * HE];
    __shared__ __align__(16) unsigned short Blds[2 * NHB * HE];

    const int tid = threadIdx.x;       // 0..511
    const int wid = tid >> 6;          // 0..7
    const int lane = tid & 63;

    // ---- staging: half = 128 rows x 64 K; 2 loads/thread; chunk c = j*512+tid;
    //      row = c>>3, oct = c&7; global octet pre-swizzled by row&7 ----
    const int goct = (tid & 7) ^ ((tid >> 3) & 7);
    const unsigned short* gA[2][2];
#pragma unroll
    for (int h = 0; h < 2; ++h)
#pragma unroll
        for (int j = 0; j < 2; ++j) {
            int rit = h * 128 + j * 64 + (tid >> 3);
            int rr = min(row0 + rit, cnt - 1);
            size_t grow = G1 ? (size_t)token_list[e * NT + rr] : (size_t)(off_e + rr);
            gA[h][j] = Abase + grow * K + goct * 8;
        }
    const unsigned short* gB[NHB][2];
#pragma unroll
    for (int h = 0; h < NHB; ++h)
#pragma unroll
        for (int j = 0; j < 2; ++j) {
            int cit = h * 128 + j * 64 + (tid >> 3);
            gB[h][j] = Wbase + ((size_t)e * NCOLS + col0 + cit) * K + goct * 8;
        }
    const int ldsj0 = (wid * 64) * 8;          // wave-uniform; HW adds lane*16B
    const int ldsj1 = (512 + wid * 64) * 8;

    auto stageA = [&](int b, int h, int k0) {
        unsigned short* d = Alds + (b * 2 + h) * HE;
        gld16(gA[h][0] + k0, d + ldsj0);
        gld16(gA[h][1] + k0, d + ldsj1);
    };
    auto stageB = [&](int b, int h, int k0) {
        unsigned short* d = Blds + (b * NHB + h) * HE;
        gld16(gB[h][0] + k0, d + ldsj0);
        gld16(gB[h][1] + k0, d + ldsj1);
    };

    // ---- fragment geometry ----
    const int wr = wid >> 2, wc = wid & 3;
    const int lrow = lane & 15;
    const int kc = lane >> 4;
    const int oct0 = kc ^ (lrow & 7);
    const int oct1 = (4 + kc) ^ (lrow & 7);
    const int bhalf = G1 ? (wc >> 1) : 0;
    const int brb   = G1 ? ((wc & 1) * 64) : (wc * 32);

    f32_4 acc[8][NF];
#pragma unroll
    for (int m = 0; m < 8; ++m)
#pragma unroll
        for (int n = 0; n < NF; ++n) acc[m][n] = (f32_4){0.f, 0.f, 0.f, 0.f};

    // prologue: stage tile 0 fully
    stageA(0, 0, 0); stageA(0, 1, 0);
    stageB(0, 0, 0);
    if constexpr (G1) stageB(0, 1, 0);

    bf16_8 breg[NF][2];

    for (int t = 0; t < NK; ++t) {
        const int b = t & 1, nb = b ^ 1;
        const int k1 = (t + 1) * 64;
        const bool pre = (t + 1 < NK);
        const unsigned short* Ab = Alds + (b * 2 + wr) * HE + lrow * 64;
        const unsigned short* Bb = Blds + (b * NHB + bhalf) * HE + (brb + lrow) * 64;

        // ===== phase 0: stage next-A0 (+A1 for G2), counted vmcnt, B+A0 reads =====
        if (pre) {
            stageA(nb, 0, k1);
            if constexpr (!G1) stageA(nb, 1, k1);
            if constexpr (G1) asm volatile("s_waitcnt vmcnt(2)" ::: "memory");
            else              asm volatile("s_waitcnt vmcnt(4)" ::: "memory");
        } else {
            asm volatile("s_waitcnt vmcnt(0)" ::: "memory");
        }
        __builtin_amdgcn_sched_barrier(0);
        __builtin_amdgcn_s_barrier();      // tile t fully resident for all waves

        {
#pragma unroll
            for (int n = 0; n < NF; ++n) {
                breg[n][0] = as_bf(*(const us8*)(Bb + n * 1024 + oct0 * 8));
                breg[n][1] = as_bf(*(const us8*)(Bb + n * 1024 + oct1 * 8));
            }
            bf16_8 ar[MGRP][2];
#pragma unroll
            for (int g = 0; g < MGRP; ++g) {
                ar[g][0] = as_bf(*(const us8*)(Ab + g * 1024 + oct0 * 8));
                ar[g][1] = as_bf(*(const us8*)(Ab + g * 1024 + oct1 * 8));
            }
            asm volatile("s_waitcnt lgkmcnt(0)" ::: "memory");
            __builtin_amdgcn_sched_barrier(0);
            __builtin_amdgcn_s_setprio(1);
#pragma unroll
            for (int g = 0; g < MGRP; ++g)
#pragma unroll
                for (int n = 0; n < NF; ++n) {
                    acc[g][n] = __builtin_amdgcn_mfma_f32_16x16x32_bf16(ar[g][0], breg[n][0], acc[g][n], 0, 0, 0);
                    acc[g][n] = __builtin_amdgcn_mfma_f32_16x16x32_bf16(ar[g][1], breg[n][1], acc[g][n], 0, 0, 0);
                }
            __builtin_amdgcn_s_setprio(0);
            __builtin_amdgcn_s_barrier();
        }

        // ===== phases 1..P-1: ds_read A-group || stage one half || 16 MFMA =====
#pragma unroll
        for (int p = 1; p < P; ++p) {
            bf16_8 ar[MGRP][2];
#pragma unroll
            for (int g = 0; g < MGRP; ++g) {
                ar[g][0] = as_bf(*(const us8*)(Ab + (p * MGRP + g) * 1024 + oct0 * 8));
                ar[g][1] = as_bf(*(const us8*)(Ab + (p * MGRP + g) * 1024 + oct1 * 8));
            }
            if (pre) {
                if constexpr (G1) {
                    if (p == 1) stageA(nb, 1, k1);
                    else if (p == 2) stageB(nb, 0, k1);
                    else stageB(nb, 1, k1);
                } else {
                    stageB(nb, 0, k1);
                }
            }
            __builtin_amdgcn_s_barrier();
            asm volatile("s_waitcnt lgkmcnt(0)" ::: "memory");
            __builtin_amdgcn_sched_barrier(0);
            __builtin_amdgcn_s_setprio(1);
#pragma unroll
            for (int g = 0; g < MGRP; ++g)
#pragma unroll
                for (int n = 0; n < NF; ++n) {
                    acc[p * MGRP + g][n] = __builtin_amdgcn_mfma_f32_16x16x32_bf16(ar[g][0], breg[n][0], acc[p * MGRP + g][n], 0, 0, 0);
                    acc[p * MGRP + g][n] = __builtin_amdgcn_mfma_f32_16x16x32_bf16(ar[g][1], breg[n][1], acc[p * MGRP + g][n], 0, 0, 0);
                }
            __builtin_amdgcn_s_setprio(0);
            __builtin_amdgcn_s_barrier();
        }
    }

    // epilogue: frag row = (lane>>4)*4 + q, col = lane&15
#pragma unroll
    for (int m = 0; m < 8; ++m) {
#pragma unroll
        for (int n = 0; n < NF; ++n) {
#pragma unroll
            for (int q = 0; q < 4; ++q) {
                int lr = wr * 128 + m * 16 + (lane >> 4) * 4 + q;
                int lc = col0 + wc * (NF * 16) + n * 16 + (lane & 15);
                int r = row0 + lr;
                if (r < cnt) {
                    float v = acc[m][n][q];
                    if constexpr (G1) {
                        v = v / (1.0f + expf(-v));  // silu
                        h_out[(size_t)(off_e + r) * DF + lc] = f2bf(v);
                    } else {
                        float g = gate_list[e * NT + r];
                        int tok = token_list[e * NT + r];
                        atomicAdd(&out[(size_t)tok * DM + lc], g * v);
                    }
                }
            }
        }
    }
}

extern "C" void kernel_launch(void* const* d_in, const int* in_sizes, int n_in,
                              void* d_out, int out_size, void* d_ws, size_t ws_size,
                              hipStream_t stream) {
    const float* x   = (const float*)d_in[0];
    const float* wrt = (const float*)d_in[1];
    const float* w1  = (const float*)d_in[2];
    const float* w2  = (const float*)d_in[3];
    float* out = (float*)d_out;

    char* ws = (char*)d_ws;
    size_t o = 0;
    auto alloc = [&](size_t bytes) { size_t r = o; o += (bytes + 255) & ~255UL; return r; };
    unsigned short* x_bf  = (unsigned short*)(ws + alloc((size_t)NT * DM * 2));
    unsigned short* w1_bf = (unsigned short*)(ws + alloc((size_t)NE * DF * DM * 2));
    unsigned short* w2_bf = (unsigned short*)(ws + alloc((size_t)NE * DM * DF * 2));
    unsigned short* h_bf  = (unsigned short*)(ws + alloc((size_t)MAXROWS * DF * 2));
    int*   counts     = (int*)(ws + alloc(NE * 4));
    int*   offsets    = (int*)(ws + alloc(NE * 4));
    int*   token_list = (int*)(ws + alloc((size_t)NE * NT * 4));
    float* gate_list  = (float*)(ws + alloc((size_t)NE * NT * 4));
    int*   eidx       = (int*)(ws + alloc((size_t)NT * 4));
    float2* gates     = (float2*)(ws + alloc((size_t)NT * 8));
    int*   tile_e     = (int*)(ws + alloc(MAXT256 * 4));
    int*   tile_r0    = (int*)(ws + alloc(MAXT256 * 4));
    int*   ntiles     = (int*)(ws + alloc(4));

    hipMemsetAsync(out, 0, (size_t)NT * DM * 4, stream);

    int n4x = NT * DM / 4;
    cast_kernel<<<(n4x + 255) / 256, 256, 0, stream>>>(x, x_bf, n4x);
    int n4w = NE * DF * DM / 4;
    cast_kernel<<<(n4w + 255) / 256, 256, 0, stream>>>(w1, w1_bf, n4w);
    cast_kernel<<<(n4w + 255) / 256, 256, 0, stream>>>(w2, w2_bf, n4w);

    router_kernel<<<NT / 4, 256, 0, stream>>>(x, wrt, eidx, gates);
    build_lists_kernel<<<NE, 256, 0, stream>>>(eidx, gates, counts, token_list, gate_list);
    scan_kernel<<<1, 64, 0, stream>>>(counts, offsets, tile_e, tile_r0, ntiles);

    // GEMM1: BN=256 -> 4 col tiles x <=72 dense 256-row tiles (~256 live blocks)
    moe_gemm<true><<<dim3(DF / 256, MAXT256, 1), 512, 0, stream>>>(
        x_bf, w1_bf, h_bf, nullptr, counts, offsets, token_list, gate_list,
        tile_e, tile_r0, ntiles);
    // GEMM2: BN=128 -> 4 col tiles x <=72 dense 256-row tiles (~256 live blocks)
    moe_gemm<false><<<dim3(DM / 128, MAXT256, 1), 512, 0, stream>>>(
        h_bf, w2_bf, nullptr, out, counts, offsets, token_list, gate_list,
        tile_e, tile_r0, ntiles);
}